// Round 7
// baseline (160.705 us; speedup 1.0000x reference)
//
#include <hip/hip_runtime.h>
#include <math.h>

#define HID 1024
#define NHEADS 16
#define NTILES 36
#define HEADSZ (36*128*64)
#define LOG2E 1.4426950408889634f
#define PLSTRIDE 73728   // 16*36*128

typedef unsigned short u16;
typedef unsigned int u32;
typedef __attribute__((ext_vector_type(8))) u16 ushort8v;
typedef __attribute__((ext_vector_type(8))) __bf16 bf16x8;
typedef __attribute__((ext_vector_type(16))) float f32x16;
typedef __attribute__((ext_vector_type(4))) u32 u32x4;

__device__ __forceinline__ u32 cvt_pk_bf16(float lo, float hi) {
  u32 r;
  asm("v_cvt_pk_bf16_f32 %0, %1, %2" : "=v"(r) : "v"(lo), "v"(hi));
  return r;
}
__device__ __forceinline__ void permlane32_swap(u32 &a, u32 &b) {
  asm volatile("v_permlane32_swap_b32 %0, %1" : "+v"(a), "+v"(b));
}
__device__ __forceinline__ void gld_lds16(const void* g, void* l) {
  __builtin_amdgcn_global_load_lds((const __attribute__((address_space(1))) u32*)g,
                                   (__attribute__((address_space(3))) u32*)l, 16, 0, 0);
}
__device__ __forceinline__ f32x16 mfma32(bf16x8 a, bf16x8 b, f32x16 c) {
  return __builtin_amdgcn_mfma_f32_32x32x16_bf16(a, b, c, 0, 0, 0);
}
__device__ __forceinline__ u16 bf16r(float x) {
  u32 b = __builtin_bit_cast(u32, x);
  b += 0x7fff + ((b >> 16) & 1);
  return (u16)(b >> 16);
}
__device__ __forceinline__ float bf2f(u16 v) {
  return __builtin_bit_cast(float, (u32)v << 16);
}

// ---------------- cast fp32 -> bf16 (5 arrays in one launch) ----------------
struct CastJob { const float* src[5]; u16* dst[5]; int n[5]; };

__global__ __launch_bounds__(256)
void cast_bf16(CastJob j) {
  const int w = blockIdx.y;
  const int n = j.n[w];
  const int i = (blockIdx.x * 256 + threadIdx.x) * 8;
  if (i >= n) return;
  const float4 v0 = *reinterpret_cast<const float4*>(j.src[w] + i);
  const float4 v1 = *reinterpret_cast<const float4*>(j.src[w] + i + 4);
  u32x4 o;
  o.x = cvt_pk_bf16(v0.x, v0.y);
  o.y = cvt_pk_bf16(v0.z, v0.w);
  o.z = cvt_pk_bf16(v1.x, v1.y);
  o.w = cvt_pk_bf16(v1.z, v1.w);
  *reinterpret_cast<u32x4*>(j.dst[w] + i) = o;
}

// ---------------- bf16 MFMA GEMM: C = A @ B^T ----------------
// M iterated in TILEIZED order (blockIdx.y = attention tile, 128 rows).
// AMODE 0: A bf16 row-major [4608][1024].  AMODE 1: A bf16 tileized.
// CMODE 0: C fp32 row-major.               CMODE 1: C bf16 tileized.
// QKV: B/C span q|k|v; heads >=32 (the V section) are written TRANSPOSED
//      ([head][tile][dh][within]) so no separate transpose pass is needed.
// DBUF: double-buffered LDS (64KB) vs single-buffer (32KB).
// NOTE (rounds 4-5): fusing the parity-merge into this GEMM's A-stage lost
// 5-8 us vs the separate merge_attn twice -> separate path is kept.
template<int AMODE, int CMODE, bool QKV, bool DBUF>
__global__ __launch_bounds__(256)
void gemm_mfma(const u16* __restrict__ A, const u16* __restrict__ B,
               void* __restrict__ Cv, float alpha)
{
    __shared__ __align__(16) u16 sm[DBUF ? 2 : 1][2][8192];

    const int tid = threadIdx.x;
    const int wv = tid >> 6, l = tid & 63;
    const int l31 = l & 31, hi = l >> 5;
    const int wm = wv >> 1, wn = wv & 1;
    const int by = blockIdx.y;
    const int n0 = blockIdx.x * 128;
    const float av = (QKV && n0 >= 1024) ? 1.0f : alpha;

    const int tt = by / 9, rem = by % 9, th = rem / 3, tw = rem % 3;
    const int tilebase = tt * 1152 + th * 192 + tw * 8;

    const int lrow = l >> 3;
    const int lslot = l & 7;
    const int sg = (lslot ^ lrow) * 8;
    const u16* aptr[4];
    const u16* bptr[4];
#pragma unroll
    for (int i = 0; i < 4; ++i) {
        const int row = (wv * 4 + i) * 8 + lrow;
        if (AMODE == 0) {
            const int s = tilebase + (row >> 6) * 576 + ((row >> 3) & 7) * 24 + (row & 7);
            aptr[i] = A + (size_t)s * HID + sg;
        } else {
            aptr[i] = A + (size_t)(by * 128 + row) * 64 + sg;
        }
        bptr[i] = B + (size_t)(n0 + row) * HID + sg;
    }

    auto stage = [&](int buf, int kc) {
#pragma unroll
        for (int i = 0; i < 4; ++i) {
            const u16* ga = (AMODE == 0) ? (aptr[i] + kc)
                                         : (aptr[i] + (size_t)(kc >> 6) * HEADSZ);
            gld_lds16(ga, &sm[buf][0][(wv * 4 + i) * 512]);
            gld_lds16(bptr[i] + kc, &sm[buf][1][(wv * 4 + i) * 512]);
        }
    };

    f32x16 acc[2][2];
#pragma unroll
    for (int mb = 0; mb < 2; ++mb)
#pragma unroll
        for (int nb = 0; nb < 2; ++nb)
#pragma unroll
            for (int i = 0; i < 16; ++i) acc[mb][nb][i] = 0.f;

    auto compute = [&](int buf) {
        __builtin_amdgcn_s_setprio(1);
#pragma unroll
        for (int kk = 0; kk < 4; ++kk) {
            bf16x8 af[2], bfr[2];
#pragma unroll
            for (int mb = 0; mb < 2; ++mb) {
                const int row = wm * 64 + mb * 32 + l31;
                af[mb] = *reinterpret_cast<const bf16x8*>(
                    &sm[buf][0][row * 64 + (((kk * 2 + hi) ^ (row & 7)) * 8)]);
            }
#pragma unroll
            for (int nb = 0; nb < 2; ++nb) {
                const int row = wn * 64 + nb * 32 + l31;
                bfr[nb] = *reinterpret_cast<const bf16x8*>(
                    &sm[buf][1][row * 64 + (((kk * 2 + hi) ^ (row & 7)) * 8)]);
            }
#pragma unroll
            for (int mb = 0; mb < 2; ++mb)
#pragma unroll
                for (int nb = 0; nb < 2; ++nb)
                    acc[mb][nb] = mfma32(af[mb], bfr[nb], acc[mb][nb]);
        }
        __builtin_amdgcn_s_setprio(0);
    };

    if (DBUF) {
        stage(0, 0);
        __syncthreads();
        int cur = 0;
        for (int kc = 0; kc < HID; kc += 64) {
            if (kc + 64 < HID) stage(cur ^ 1, kc + 64);
            compute(cur);
            __syncthreads();
            cur ^= 1;
        }
    } else {
        for (int kc = 0; kc < HID; kc += 64) {
            __syncthreads();
            stage(0, kc);
            __syncthreads();
            compute(0);
        }
    }

    if (CMODE == 0) {
        float* C = (float*)Cv;
#pragma unroll
        for (int mb = 0; mb < 2; ++mb)
#pragma unroll
            for (int r = 0; r < 16; ++r) {
                const int m = wm * 64 + mb * 32 + (r & 3) + 8 * (r >> 2) + 4 * hi;
                const int s = tilebase + (m >> 6) * 576 + ((m >> 3) & 7) * 24 + (m & 7);
#pragma unroll
                for (int nb = 0; nb < 2; ++nb) {
                    const int n = n0 + wn * 64 + nb * 32 + l31;
                    C[(size_t)s * HID + n] = acc[mb][nb][r] * av;
                }
            }
    } else {
        u16* C = (u16*)Cv;
#pragma unroll
        for (int mb = 0; mb < 2; ++mb)
#pragma unroll
            for (int rq = 0; rq < 4; ++rq) {
                const int mbase = wm * 64 + mb * 32 + 8 * rq + 4 * hi;
#pragma unroll
                for (int nb = 0; nb < 2; ++nb) {
                    const int n = n0 + wn * 64 + nb * 32 + l31;
                    const int head = n >> 6, dh = n & 63;
                    if (QKV && head >= 32) {
                        // V: write transposed [head][tile][dh][within]
                        u32 w0 = cvt_pk_bf16(acc[mb][nb][rq * 4 + 0], acc[mb][nb][rq * 4 + 1]);
                        u32 w1 = cvt_pk_bf16(acc[mb][nb][rq * 4 + 2], acc[mb][nb][rq * 4 + 3]);
                        *reinterpret_cast<uint2*>(C + (size_t)head * HEADSZ +
                            (size_t)by * 8192 + dh * 128 + mbase) = make_uint2(w0, w1);
                    } else {
#pragma unroll
                        for (int j = 0; j < 4; ++j) {
                            const int m = mbase + j;
                            C[(size_t)head * HEADSZ + (size_t)(by * 128 + m) * 64 + dh] =
                                bf16r(acc[mb][nb][rq * 4 + j] * av);
                        }
                    }
                }
            }
    }
}

// attention: 1152 blocks = (head, q-tile, key-parity); 4 waves x 32 q-rows.
// parity p handles the p-th 64-key half of each of the 27 neighbor tiles.
// Round-6 accounting: issue work is only ~25% of wall -> massive stalls with
// ~2 waves/SIMD resident. Theory: s_setprio is a compiler SCHEDULING BARRIER
// (intrinsic w/ side effects); 6 per iter fenced every MFMA cluster so the two
// independent 32-key chains (c=0,c=1) ran phase-serial with zero same-wave ILP.
// This round: remove setprio from attn + interleave the c-chains at source
// level (QK0||QK1 alternating MFMAs, softmax both, pack both, PV both).
// Identical instruction count, reordered. Spill sentinel: WRITE_SIZE 19008.
// No-max softmax -> partials merge by pure addition in merge_attn.
// XCD-swizzled blockIdx: each XCD owns 2 heads (K/V fit its 4MB L2).
__global__ __launch_bounds__(256, 4)
void attn_mfma(const u16* __restrict__ Q, const u16* __restrict__ K,
               const u16* __restrict__ Vt, u16* __restrict__ pO0,
               u16* __restrict__ pO1, float* __restrict__ pl)
{
    __shared__ u16 sm[2][2][4096];   // [buf][K=0 / V=1][64 x 64] = 32 KB

    const int tid = threadIdx.x;
    const int wave = tid >> 6;
    const int lane = tid & 63;
    const int l31 = lane & 31;
    const int hi  = lane >> 5;

    // XCD-aware bijective swizzle: 1152 = 8 * 144
    const int logical = (blockIdx.x & 7) * 144 + (blockIdx.x >> 3);
    const int p  = logical & 1;
    const int bt = logical >> 1;       // head*36 + tile
    const int tl = bt % NTILES;
    const int hd = bt / NTILES;
    const size_t headbase = (size_t)hd * HEADSZ;

    const u16* Qg = Q + headbase + (size_t)tl * 8192;
    const u16* Kh = K + headbase;
    const u16* Vh = Vt + headbase;

    bf16x8 qf[4];
    {
        const u16* qrow = Qg + (wave * 32 + l31) * 64 + hi * 8;
#pragma unroll
        for (int ks = 0; ks < 4; ++ks)
            qf[ks] = *reinterpret_cast<const bf16x8*>(qrow + ks * 16);
    }

    const int base_t = (min(max(tl / 9, 1), 2) - 1) * 9;

    const int srow = lane >> 3;   // 0..7
    const int slot = lane & 7;

    auto stage = [&](int i, int bi) {
        const int kt = base_t + i;
        const u16* Kg = Kh + (size_t)kt * 8192 + p * 4096;
        const u16* Vg = Vh + (size_t)kt * 8192 + p * 64;
        u16* dk = &sm[bi][0][0];
        u16* dv = &sm[bi][1][0];
#pragma unroll
        for (int q = 0; q < 2; ++q) {
            const int seg = wave * 2 + q;
            const int key = seg * 8 + srow;
            gld_lds16(Kg + key * 64 + ((slot ^ (key & 7)) * 8), dk + seg * 512);
            const int dh = seg * 8 + srow;
            gld_lds16(Vg + dh * 128 + ((slot ^ (dh & 7)) * 8), dv + seg * 512);
        }
    };

    f32x16 accO0, accO1;
#pragma unroll
    for (int i = 0; i < 16; ++i) { accO0[i] = 0.f; accO1[i] = 0.f; }
    float lsum = 0.f;

    auto packP = [&](const f32x16& s, bf16x8* pb) {
        u32 a0 = cvt_pk_bf16(s[0], s[1]);
        u32 a1 = cvt_pk_bf16(s[2], s[3]);
        u32 b0 = cvt_pk_bf16(s[4], s[5]);
        u32 b1 = cvt_pk_bf16(s[6], s[7]);
        permlane32_swap(a0, b0);
        permlane32_swap(a1, b1);
        u32x4 w; w.x = a0; w.y = a1; w.z = b0; w.w = b1;
        pb[0] = __builtin_bit_cast(bf16x8, w);
        u32 c0 = cvt_pk_bf16(s[8], s[9]);
        u32 c1 = cvt_pk_bf16(s[10], s[11]);
        u32 d0 = cvt_pk_bf16(s[12], s[13]);
        u32 d1 = cvt_pk_bf16(s[14], s[15]);
        permlane32_swap(c0, d0);
        permlane32_swap(c1, d1);
        u32x4 w2; w2.x = c0; w2.y = c1; w2.z = d0; w2.w = d1;
        pb[1] = __builtin_bit_cast(bf16x8, w2);
    };

    stage(0, 0);
    __syncthreads();

    for (int i = 0; i < 27; ++i) {
        const int cur = i & 1;
        if (i + 1 < 27) stage(i + 1, cur ^ 1);
        const u16* Ksb = &sm[cur][0][0];
        const u16* Vsb = &sm[cur][1][0];

        // QK^T for BOTH 32-key halves, alternating: 2 independent MFMA chains
        f32x16 s0, s1;
#pragma unroll
        for (int i2 = 0; i2 < 16; ++i2) { s0[i2] = 0.f; s1[i2] = 0.f; }
        const int kr0 = l31;
        const int kr1 = 32 + l31;
#pragma unroll
        for (int ks = 0; ks < 4; ++ks) {
            bf16x8 a0 = *reinterpret_cast<const bf16x8*>(
                Ksb + kr0 * 64 + (((2 * ks + hi) ^ (kr0 & 7)) * 8));
            s0 = mfma32(a0, qf[ks], s0);
            bf16x8 a1 = *reinterpret_cast<const bf16x8*>(
                Ksb + kr1 * 64 + (((2 * ks + hi) ^ (kr1 & 7)) * 8));
            s1 = mfma32(a1, qf[ks], s1);
        }

        // softmax both halves (plain exp2; scores pre-scaled by log2e/8 in Q)
#pragma unroll
        for (int i2 = 0; i2 < 16; ++i2) s0[i2] = __builtin_amdgcn_exp2f(s0[i2]);
#pragma unroll
        for (int i2 = 0; i2 < 16; ++i2) s1[i2] = __builtin_amdgcn_exp2f(s1[i2]);
        float ps0 = 0.f, ps1 = 0.f;
#pragma unroll
        for (int i2 = 0; i2 < 16; ++i2) { ps0 += s0[i2]; ps1 += s1[i2]; }
        lsum += ps0 + ps1;

        // pack both P halves -> bf16 B-frags
        bf16x8 pb0[2], pb1[2];
        packP(s0, pb0);
        packP(s1, pb1);

        // PV: both halves (accO chains interleave across c via the scheduler)
#pragma unroll
        for (int k2 = 0; k2 < 2; ++k2) {
            const int sgA = k2 * 2 + hi;            // c = 0 key slices
            bf16x8 v0 = *reinterpret_cast<const bf16x8*>(
                Vsb + l31 * 64 + ((sgA ^ (l31 & 7)) * 8));
            accO0 = mfma32(v0, pb0[k2], accO0);
            bf16x8 v1 = *reinterpret_cast<const bf16x8*>(
                Vsb + (32 + l31) * 64 + ((sgA ^ (l31 & 7)) * 8));
            accO1 = mfma32(v1, pb0[k2], accO1);
        }
#pragma unroll
        for (int k2 = 0; k2 < 2; ++k2) {
            const int sgB = 4 + k2 * 2 + hi;        // c = 1 key slices
            bf16x8 v0 = *reinterpret_cast<const bf16x8*>(
                Vsb + l31 * 64 + ((sgB ^ (l31 & 7)) * 8));
            accO0 = mfma32(v0, pb1[k2], accO0);
            bf16x8 v1 = *reinterpret_cast<const bf16x8*>(
                Vsb + (32 + l31) * 64 + ((sgB ^ (l31 & 7)) * 8));
            accO1 = mfma32(v1, pb1[k2], accO1);
        }
        __syncthreads();
    }

    lsum += __shfl_xor(lsum, 32);

    u16* Ob = (p ? pO1 : pO0) + ((size_t)bt * 128 + wave * 32 + l31) * 64;
#pragma unroll
    for (int t = 0; t < 4; ++t) {
        u32 p0 = cvt_pk_bf16(accO0[4 * t], accO0[4 * t + 1]);
        u32 p1 = cvt_pk_bf16(accO0[4 * t + 2], accO0[4 * t + 3]);
        *reinterpret_cast<uint2*>(Ob + t * 8 + 4 * hi) = make_uint2(p0, p1);
        u32 q0 = cvt_pk_bf16(accO1[4 * t], accO1[4 * t + 1]);
        u32 q1 = cvt_pk_bf16(accO1[4 * t + 2], accO1[4 * t + 3]);
        *reinterpret_cast<uint2*>(Ob + 32 + t * 8 + 4 * hi) = make_uint2(q0, q1);
    }
    if (hi == 0) pl[p * PLSTRIDE + bt * 128 + wave * 32 + l31] = lsum;
}

// merge the two key-parity partials: O = (pO0 + pO1) / (l0 + l1), bf16 tileized
__global__ __launch_bounds__(256)
void merge_attn(const u16* __restrict__ pO0, const u16* __restrict__ pO1,
                const float* __restrict__ pl, u16* __restrict__ O)
{
    const int b = blockIdx.x;          // head*36 + tile
    const int tid = threadIdx.x;
    const int row = tid >> 1;
    const int d0 = (tid & 1) * 32;
    const size_t rbase = ((size_t)b * 128 + row) * 64 + d0;
    const float inv = 1.f / (pl[b * 128 + row] + pl[PLSTRIDE + b * 128 + row]);
#pragma unroll
    for (int g = 0; g < 4; ++g) {
        ushort8v a = *reinterpret_cast<const ushort8v*>(pO0 + rbase + g * 8);
        ushort8v c = *reinterpret_cast<const ushort8v*>(pO1 + rbase + g * 8);
        u32 w[4];
#pragma unroll
        for (int h = 0; h < 4; ++h) {
            float f0 = (bf2f(a[2 * h])     + bf2f(c[2 * h]))     * inv;
            float f1 = (bf2f(a[2 * h + 1]) + bf2f(c[2 * h + 1])) * inv;
            w[h] = cvt_pk_bf16(f0, f1);
        }
        u32x4 st; st.x = w[0]; st.y = w[1]; st.z = w[2]; st.w = w[3];
        *reinterpret_cast<u32x4*>(O + rbase + g * 8) = st;
    }
}

extern "C" void kernel_launch(void* const* d_in, const int* in_sizes, int n_in,
                              void* d_out, int out_size, void* d_ws, size_t ws_size,
                              hipStream_t stream) {
    const float* hs = (const float*)d_in[0];
    const float* qw = (const float*)d_in[1];
    const float* kw = (const float*)d_in[2];
    const float* vw = (const float*)d_in[3];
    const float* ow = (const float*)d_in[4];
    float* out = (float*)d_out;

    const size_t TSZ = (size_t)NHEADS * HEADSZ;
    const size_t WSZ = (size_t)HID * HID;
    u16* hsb = (u16*)d_ws;      // reused as pO0 after the QKV GEMM consumes hs
    u16* wqb = hsb + TSZ;       // wq|wk|wv|wo contiguous
    u16* wkb = wqb + WSZ;
    u16* wvb = wkb + WSZ;
    u16* wob = wvb + WSZ;
    u16* qb  = wob + WSZ;       // q|k|vt contiguous (from fused QKV gemm)
    u16* kb  = qb + TSZ;
    u16* vt  = kb + TSZ;
    u16* pO0 = hsb;
    u16* pO1 = vt + TSZ;
    float* pl = (float*)(pO1 + TSZ);
    u16* aob = (u16*)(pl + 2 * PLSTRIDE);

    CastJob cj;
    cj.src[0] = hs; cj.dst[0] = hsb; cj.n[0] = (int)TSZ;
    cj.src[1] = qw; cj.dst[1] = wqb; cj.n[1] = (int)WSZ;
    cj.src[2] = kw; cj.dst[2] = wkb; cj.n[2] = (int)WSZ;
    cj.src[3] = vw; cj.dst[3] = wvb; cj.n[3] = (int)WSZ;
    cj.src[4] = ow; cj.dst[4] = wob; cj.n[4] = (int)WSZ;
    cast_bf16<<<dim3(2304, 5), 256, 0, stream>>>(cj);

    // fused QKV projection (V written pre-transposed)
    gemm_mfma<0, 1, true, true><<<dim3(24, 36), 256, 0, stream>>>(hsb, wqb, qb, 0.125f * LOG2E);
    attn_mfma<<<NHEADS * NTILES * 2, 256, 0, stream>>>(qb, kb, vt, pO0, pO1, pl);
    merge_attn<<<NHEADS * NTILES, 256, 0, stream>>>(pO0, pO1, pl, aob);
    gemm_mfma<1, 0, false, true><<<dim3(8, 36), 256, 0, stream>>>(aob, wob, out, 1.0f);
}

// Round 8
// 156.497 us; speedup vs baseline: 1.0269x; 1.0269x over previous
//
#include <hip/hip_runtime.h>
#include <math.h>

#define HID 1024
#define NHEADS 16
#define NTILES 36
#define HEADSZ (36*128*64)
#define LOG2E 1.4426950408889634f
#define PLSTRIDE 73728   // 16*36*128

typedef unsigned short u16;
typedef unsigned int u32;
typedef __attribute__((ext_vector_type(8))) u16 ushort8v;
typedef __attribute__((ext_vector_type(8))) __bf16 bf16x8;
typedef __attribute__((ext_vector_type(16))) float f32x16;
typedef __attribute__((ext_vector_type(4))) u32 u32x4;

__device__ __forceinline__ u32 cvt_pk_bf16(float lo, float hi) {
  u32 r;
  asm("v_cvt_pk_bf16_f32 %0, %1, %2" : "=v"(r) : "v"(lo), "v"(hi));
  return r;
}
__device__ __forceinline__ void permlane32_swap(u32 &a, u32 &b) {
  asm volatile("v_permlane32_swap_b32 %0, %1" : "+v"(a), "+v"(b));
}
__device__ __forceinline__ void gld_lds16(const void* g, void* l) {
  __builtin_amdgcn_global_load_lds((const __attribute__((address_space(1))) u32*)g,
                                   (__attribute__((address_space(3))) u32*)l, 16, 0, 0);
}
__device__ __forceinline__ f32x16 mfma32(bf16x8 a, bf16x8 b, f32x16 c) {
  return __builtin_amdgcn_mfma_f32_32x32x16_bf16(a, b, c, 0, 0, 0);
}
__device__ __forceinline__ u16 bf16r(float x) {
  u32 b = __builtin_bit_cast(u32, x);
  b += 0x7fff + ((b >> 16) & 1);
  return (u16)(b >> 16);
}
__device__ __forceinline__ float bf2f(u16 v) {
  return __builtin_bit_cast(float, (u32)v << 16);
}

// ---------------- cast fp32 -> bf16 (5 arrays in one launch) ----------------
struct CastJob { const float* src[5]; u16* dst[5]; int n[5]; };

__global__ __launch_bounds__(256)
void cast_bf16(CastJob j) {
  const int w = blockIdx.y;
  const int n = j.n[w];
  const int i = (blockIdx.x * 256 + threadIdx.x) * 8;
  if (i >= n) return;
  const float4 v0 = *reinterpret_cast<const float4*>(j.src[w] + i);
  const float4 v1 = *reinterpret_cast<const float4*>(j.src[w] + i + 4);
  u32x4 o;
  o.x = cvt_pk_bf16(v0.x, v0.y);
  o.y = cvt_pk_bf16(v0.z, v0.w);
  o.z = cvt_pk_bf16(v1.x, v1.y);
  o.w = cvt_pk_bf16(v1.z, v1.w);
  *reinterpret_cast<u32x4*>(j.dst[w] + i) = o;
}

// ---------------- bf16 MFMA GEMM: C = A @ B^T ----------------
// M iterated in TILEIZED order (blockIdx.y = attention tile, 128 rows).
// AMODE 0: A bf16 row-major [4608][1024].  AMODE 1: A bf16 tileized.
// CMODE 0: C fp32 row-major.               CMODE 1: C bf16 tileized.
// QKV: B/C span q|k|v; heads >=32 (the V section) are written in the
//      direct-PV layout [head][tile][chunk16][dh64][key8] so attn can read
//      V fragments straight from L2 with perfectly coalesced 1KB loads
//      (no LDS staging of V at all; round-8 change).
// DBUF: double-buffered LDS (64KB) vs single-buffer (32KB).
// NOTE (rounds 4-5): fusing the parity-merge into this GEMM's A-stage lost
// 5-8 us vs the separate merge_attn twice -> separate path is kept.
template<int AMODE, int CMODE, bool QKV, bool DBUF>
__global__ __launch_bounds__(256)
void gemm_mfma(const u16* __restrict__ A, const u16* __restrict__ B,
               void* __restrict__ Cv, float alpha)
{
    __shared__ __align__(16) u16 sm[DBUF ? 2 : 1][2][8192];

    const int tid = threadIdx.x;
    const int wv = tid >> 6, l = tid & 63;
    const int l31 = l & 31, hi = l >> 5;
    const int wm = wv >> 1, wn = wv & 1;
    const int by = blockIdx.y;
    const int n0 = blockIdx.x * 128;
    const float av = (QKV && n0 >= 1024) ? 1.0f : alpha;

    const int tt = by / 9, rem = by % 9, th = rem / 3, tw = rem % 3;
    const int tilebase = tt * 1152 + th * 192 + tw * 8;

    const int lrow = l >> 3;
    const int lslot = l & 7;
    const int sg = (lslot ^ lrow) * 8;
    const u16* aptr[4];
    const u16* bptr[4];
#pragma unroll
    for (int i = 0; i < 4; ++i) {
        const int row = (wv * 4 + i) * 8 + lrow;
        if (AMODE == 0) {
            const int s = tilebase + (row >> 6) * 576 + ((row >> 3) & 7) * 24 + (row & 7);
            aptr[i] = A + (size_t)s * HID + sg;
        } else {
            aptr[i] = A + (size_t)(by * 128 + row) * 64 + sg;
        }
        bptr[i] = B + (size_t)(n0 + row) * HID + sg;
    }

    auto stage = [&](int buf, int kc) {
#pragma unroll
        for (int i = 0; i < 4; ++i) {
            const u16* ga = (AMODE == 0) ? (aptr[i] + kc)
                                         : (aptr[i] + (size_t)(kc >> 6) * HEADSZ);
            gld_lds16(ga, &sm[buf][0][(wv * 4 + i) * 512]);
            gld_lds16(bptr[i] + kc, &sm[buf][1][(wv * 4 + i) * 512]);
        }
    };

    f32x16 acc[2][2];
#pragma unroll
    for (int mb = 0; mb < 2; ++mb)
#pragma unroll
        for (int nb = 0; nb < 2; ++nb)
#pragma unroll
            for (int i = 0; i < 16; ++i) acc[mb][nb][i] = 0.f;

    auto compute = [&](int buf) {
        __builtin_amdgcn_s_setprio(1);
#pragma unroll
        for (int kk = 0; kk < 4; ++kk) {
            bf16x8 af[2], bfr[2];
#pragma unroll
            for (int mb = 0; mb < 2; ++mb) {
                const int row = wm * 64 + mb * 32 + l31;
                af[mb] = *reinterpret_cast<const bf16x8*>(
                    &sm[buf][0][row * 64 + (((kk * 2 + hi) ^ (row & 7)) * 8)]);
            }
#pragma unroll
            for (int nb = 0; nb < 2; ++nb) {
                const int row = wn * 64 + nb * 32 + l31;
                bfr[nb] = *reinterpret_cast<const bf16x8*>(
                    &sm[buf][1][row * 64 + (((kk * 2 + hi) ^ (row & 7)) * 8)]);
            }
#pragma unroll
            for (int mb = 0; mb < 2; ++mb)
#pragma unroll
                for (int nb = 0; nb < 2; ++nb)
                    acc[mb][nb] = mfma32(af[mb], bfr[nb], acc[mb][nb]);
        }
        __builtin_amdgcn_s_setprio(0);
    };

    if (DBUF) {
        stage(0, 0);
        __syncthreads();
        int cur = 0;
        for (int kc = 0; kc < HID; kc += 64) {
            if (kc + 64 < HID) stage(cur ^ 1, kc + 64);
            compute(cur);
            __syncthreads();
            cur ^= 1;
        }
    } else {
        for (int kc = 0; kc < HID; kc += 64) {
            __syncthreads();
            stage(0, kc);
            __syncthreads();
            compute(0);
        }
    }

    if (CMODE == 0) {
        float* C = (float*)Cv;
#pragma unroll
        for (int mb = 0; mb < 2; ++mb)
#pragma unroll
            for (int r = 0; r < 16; ++r) {
                const int m = wm * 64 + mb * 32 + (r & 3) + 8 * (r >> 2) + 4 * hi;
                const int s = tilebase + (m >> 6) * 576 + ((m >> 3) & 7) * 24 + (m & 7);
#pragma unroll
                for (int nb = 0; nb < 2; ++nb) {
                    const int n = n0 + wn * 64 + nb * 32 + l31;
                    C[(size_t)s * HID + n] = acc[mb][nb][r] * av;
                }
            }
    } else {
        u16* C = (u16*)Cv;
#pragma unroll
        for (int mb = 0; mb < 2; ++mb)
#pragma unroll
            for (int rq = 0; rq < 4; ++rq) {
                const int mbase = wm * 64 + mb * 32 + 8 * rq + 4 * hi;
#pragma unroll
                for (int nb = 0; nb < 2; ++nb) {
                    const int n = n0 + wn * 64 + nb * 32 + l31;
                    const int head = n >> 6, dh = n & 63;
                    if (QKV && head >= 32) {
                        // V: write in direct-PV layout [chunk16][dh64][key8].
                        // keys mbase..mbase+3 stay within one 8-key chunk
                        // (mbase%8 in {0,4}).
                        u32 w0 = cvt_pk_bf16(acc[mb][nb][rq * 4 + 0], acc[mb][nb][rq * 4 + 1]);
                        u32 w1 = cvt_pk_bf16(acc[mb][nb][rq * 4 + 2], acc[mb][nb][rq * 4 + 3]);
                        *reinterpret_cast<uint2*>(C + (size_t)head * HEADSZ +
                            (size_t)by * 8192 + (mbase >> 3) * 512 + (dh << 3) +
                            (mbase & 7)) = make_uint2(w0, w1);
                    } else {
#pragma unroll
                        for (int j = 0; j < 4; ++j) {
                            const int m = mbase + j;
                            C[(size_t)head * HEADSZ + (size_t)(by * 128 + m) * 64 + dh] =
                                bf16r(acc[mb][nb][rq * 4 + j] * av);
                        }
                    }
                }
            }
    }
}

// attention: 1152 blocks = (head, q-tile, key-parity); 4 waves x 32 q-rows.
// parity p handles the p-th 64-key half of each of the 27 neighbor tiles.
// Round-0 inner loop (serial c + setprio; round-7 interleave was a net loss).
// Round-8 change (m169 precedent: staging L2-fit data is pure overhead):
// V is NOT staged in LDS. K/V per head = 1.2MB, L2-resident (XCD swizzle);
// V fragments are read directly from L2 via the [chunk16][dh64][key8] layout
// (two contiguous 512B runs per b128 load, perfectly coalesced). The loads
// issue before QK so ~500cy of QK+softmax hides L2 latency. LDS 32->16KB,
// V's share of LDS-port traffic, bank conflicts and barrier-drain removed.
// Direct-V L2 traffic ~22 B/cyc/CU, well under the ~56 B/cyc/CU L2 ceiling.
// No-max softmax -> partials merge by pure addition in merge_attn.
// XCD-swizzled blockIdx: each XCD owns 2 heads (K/V fit its 4MB L2).
__global__ __launch_bounds__(256, 4)
void attn_mfma(const u16* __restrict__ Q, const u16* __restrict__ K,
               const u16* __restrict__ Vt, u16* __restrict__ pO0,
               u16* __restrict__ pO1, float* __restrict__ pl)
{
    __shared__ u16 sm[2][4096];   // [buf][K 64 x 64] = 16 KB (K only)

    const int tid = threadIdx.x;
    const int wave = tid >> 6;
    const int lane = tid & 63;
    const int l31 = lane & 31;
    const int hi  = lane >> 5;

    // XCD-aware bijective swizzle: 1152 = 8 * 144
    const int logical = (blockIdx.x & 7) * 144 + (blockIdx.x >> 3);
    const int p  = logical & 1;
    const int bt = logical >> 1;       // head*36 + tile
    const int tl = bt % NTILES;
    const int hd = bt / NTILES;
    const size_t headbase = (size_t)hd * HEADSZ;

    const u16* Qg = Q + headbase + (size_t)tl * 8192;
    const u16* Kh = K + headbase;
    const u16* Vh = Vt + headbase;

    bf16x8 qf[4];
    {
        const u16* qrow = Qg + (wave * 32 + l31) * 64 + hi * 8;
#pragma unroll
        for (int ks = 0; ks < 4; ++ks)
            qf[ks] = *reinterpret_cast<const bf16x8*>(qrow + ks * 16);
    }

    const int base_t = (min(max(tl / 9, 1), 2) - 1) * 9;

    const int srow = lane >> 3;   // 0..7
    const int slot = lane & 7;

    auto stage = [&](int i, int bi) {
        const int kt = base_t + i;
        const u16* Kg = Kh + (size_t)kt * 8192 + p * 4096;
        u16* dk = &sm[bi][0];
#pragma unroll
        for (int q = 0; q < 2; ++q) {
            const int seg = wave * 2 + q;
            const int key = seg * 8 + srow;
            gld_lds16(Kg + key * 64 + ((slot ^ (key & 7)) * 8), dk + seg * 512);
        }
    };

    f32x16 accO0, accO1;
#pragma unroll
    for (int i = 0; i < 16; ++i) { accO0[i] = 0.f; accO1[i] = 0.f; }
    float lsum = 0.f;

    stage(0, 0);
    __syncthreads();

    for (int i = 0; i < 27; ++i) {
        const int cur = i & 1;
        if (i + 1 < 27) stage(i + 1, cur ^ 1);
        const u16* Ksb = &sm[cur][0];
        const u16* Vg = Vh + (size_t)(base_t + i) * 8192;

#pragma unroll
        for (int c = 0; c < 2; ++c) {
            // V fragments direct from L2 (issued early; used after QK+softmax)
            bf16x8 vf[2][2];
#pragma unroll
            for (int k2 = 0; k2 < 2; ++k2) {
                const int chunk = 8 * p + 4 * c + 2 * k2 + hi;
                const u16* vb = Vg + chunk * 512 + l31 * 8;
                vf[k2][0] = *reinterpret_cast<const bf16x8*>(vb);
                vf[k2][1] = *reinterpret_cast<const bf16x8*>(vb + 256);
            }

            f32x16 s;
#pragma unroll
            for (int i2 = 0; i2 < 16; ++i2) s[i2] = 0.f;
            const int kr = c * 32 + l31;
            __builtin_amdgcn_s_setprio(1);
#pragma unroll
            for (int ks = 0; ks < 4; ++ks) {
                bf16x8 a = *reinterpret_cast<const bf16x8*>(
                    Ksb + kr * 64 + (((2 * ks + hi) ^ (kr & 7)) * 8));
                s = mfma32(a, qf[ks], s);
            }
            __builtin_amdgcn_s_setprio(0);

            // plain exp2 (scores pre-scaled by log2e/8 in Q; bounded, no max)
#pragma unroll
            for (int i2 = 0; i2 < 16; ++i2) s[i2] = __builtin_amdgcn_exp2f(s[i2]);

            float ps = 0.f;
#pragma unroll
            for (int i2 = 0; i2 < 16; ++i2) ps += s[i2];
            lsum += ps;

            // pack P -> 2 bf16 B-frags (32 keys)
            bf16x8 pb[2];
            {
                u32 a0 = cvt_pk_bf16(s[0], s[1]);
                u32 a1 = cvt_pk_bf16(s[2], s[3]);
                u32 b0 = cvt_pk_bf16(s[4], s[5]);
                u32 b1 = cvt_pk_bf16(s[6], s[7]);
                permlane32_swap(a0, b0);
                permlane32_swap(a1, b1);
                u32x4 w; w.x = a0; w.y = a1; w.z = b0; w.w = b1;
                pb[0] = __builtin_bit_cast(bf16x8, w);
                u32 c0 = cvt_pk_bf16(s[8], s[9]);
                u32 c1 = cvt_pk_bf16(s[10], s[11]);
                u32 d0 = cvt_pk_bf16(s[12], s[13]);
                u32 d1 = cvt_pk_bf16(s[14], s[15]);
                permlane32_swap(c0, d0);
                permlane32_swap(c1, d1);
                u32x4 w2; w2.x = c0; w2.y = c1; w2.z = d0; w2.w = d1;
                pb[1] = __builtin_bit_cast(bf16x8, w2);
            }

            __builtin_amdgcn_s_setprio(1);
#pragma unroll
            for (int k2 = 0; k2 < 2; ++k2) {
                accO0 = mfma32(vf[k2][0], pb[k2], accO0);
                accO1 = mfma32(vf[k2][1], pb[k2], accO1);
            }
            __builtin_amdgcn_s_setprio(0);
        }
        __syncthreads();
    }

    lsum += __shfl_xor(lsum, 32);

    u16* Ob = (p ? pO1 : pO0) + ((size_t)bt * 128 + wave * 32 + l31) * 64;
#pragma unroll
    for (int t = 0; t < 4; ++t) {
        u32 p0 = cvt_pk_bf16(accO0[4 * t], accO0[4 * t + 1]);
        u32 p1 = cvt_pk_bf16(accO0[4 * t + 2], accO0[4 * t + 3]);
        *reinterpret_cast<uint2*>(Ob + t * 8 + 4 * hi) = make_uint2(p0, p1);
        u32 q0 = cvt_pk_bf16(accO1[4 * t], accO1[4 * t + 1]);
        u32 q1 = cvt_pk_bf16(accO1[4 * t + 2], accO1[4 * t + 3]);
        *reinterpret_cast<uint2*>(Ob + 32 + t * 8 + 4 * hi) = make_uint2(q0, q1);
    }
    if (hi == 0) pl[p * PLSTRIDE + bt * 128 + wave * 32 + l31] = lsum;
}

// merge the two key-parity partials: O = (pO0 + pO1) / (l0 + l1), bf16 tileized
__global__ __launch_bounds__(256)
void merge_attn(const u16* __restrict__ pO0, const u16* __restrict__ pO1,
                const float* __restrict__ pl, u16* __restrict__ O)
{
    const int b = blockIdx.x;          // head*36 + tile
    const int tid = threadIdx.x;
    const int row = tid >> 1;
    const int d0 = (tid & 1) * 32;
    const size_t rbase = ((size_t)b * 128 + row) * 64 + d0;
    const float inv = 1.f / (pl[b * 128 + row] + pl[PLSTRIDE + b * 128 + row]);
#pragma unroll
    for (int g = 0; g < 4; ++g) {
        ushort8v a = *reinterpret_cast<const ushort8v*>(pO0 + rbase + g * 8);
        ushort8v c = *reinterpret_cast<const ushort8v*>(pO1 + rbase + g * 8);
        u32 w[4];
#pragma unroll
        for (int h = 0; h < 4; ++h) {
            float f0 = (bf2f(a[2 * h])     + bf2f(c[2 * h]))     * inv;
            float f1 = (bf2f(a[2 * h + 1]) + bf2f(c[2 * h + 1])) * inv;
            w[h] = cvt_pk_bf16(f0, f1);
        }
        u32x4 st; st.x = w[0]; st.y = w[1]; st.z = w[2]; st.w = w[3];
        *reinterpret_cast<u32x4*>(O + rbase + g * 8) = st;
    }
}

extern "C" void kernel_launch(void* const* d_in, const int* in_sizes, int n_in,
                              void* d_out, int out_size, void* d_ws, size_t ws_size,
                              hipStream_t stream) {
    const float* hs = (const float*)d_in[0];
    const float* qw = (const float*)d_in[1];
    const float* kw = (const float*)d_in[2];
    const float* vw = (const float*)d_in[3];
    const float* ow = (const float*)d_in[4];
    float* out = (float*)d_out;

    const size_t TSZ = (size_t)NHEADS * HEADSZ;
    const size_t WSZ = (size_t)HID * HID;
    u16* hsb = (u16*)d_ws;      // reused as pO0 after the QKV GEMM consumes hs
    u16* wqb = hsb + TSZ;       // wq|wk|wv|wo contiguous
    u16* wkb = wqb + WSZ;
    u16* wvb = wkb + WSZ;
    u16* wob = wvb + WSZ;
    u16* qb  = wob + WSZ;       // q|k|vt contiguous (from fused QKV gemm)
    u16* kb  = qb + TSZ;
    u16* vt  = kb + TSZ;
    u16* pO0 = hsb;
    u16* pO1 = vt + TSZ;
    float* pl = (float*)(pO1 + TSZ);
    u16* aob = (u16*)(pl + 2 * PLSTRIDE);

    CastJob cj;
    cj.src[0] = hs; cj.dst[0] = hsb; cj.n[0] = (int)TSZ;
    cj.src[1] = qw; cj.dst[1] = wqb; cj.n[1] = (int)WSZ;
    cj.src[2] = kw; cj.dst[2] = wkb; cj.n[2] = (int)WSZ;
    cj.src[3] = vw; cj.dst[3] = wvb; cj.n[3] = (int)WSZ;
    cj.src[4] = ow; cj.dst[4] = wob; cj.n[4] = (int)WSZ;
    cast_bf16<<<dim3(2304, 5), 256, 0, stream>>>(cj);

    // fused QKV projection (V written in the direct-PV layout)
    gemm_mfma<0, 1, true, true><<<dim3(24, 36), 256, 0, stream>>>(hsb, wqb, qb, 0.125f * LOG2E);
    attn_mfma<<<NHEADS * NTILES * 2, 256, 0, stream>>>(qb, kb, vt, pO0, pO1, pl);
    merge_attn<<<NHEADS * NTILES, 256, 0, stream>>>(pO0, pO1, pl, aob);
    gemm_mfma<1, 0, false, true><<<dim3(8, 36), 256, 0, stream>>>(aob, wob, out, 1.0f);
}